// Round 1
// baseline (43280.511 us; speedup 1.0000x reference)
//
#include <hip/hip_runtime.h>
#include <math.h>

#define NBOND 7
#define NLAY 8
#define NTYPE 6
#define NNODES 16384   // B*N = 128*128

__device__ __forceinline__ float sig_(float x) { return 1.0f / (1.0f + __expf(-x)); }

// ---------------------------------------------------------------- setup:
// h_t = concat(h, zeros) into d_out; bucket nodes by atom type (channel 0).
__global__ void setup_kernel(const float* __restrict__ h, float* __restrict__ hT,
                             int* __restrict__ counts, int* __restrict__ bucket)
{
    int gid = blockIdx.x * 256 + threadIdx.x;          // 0 .. 2M-1
    int node = gid >> 7, d = gid & 127;
    hT[gid] = (d < 75) ? h[node * 75 + d] : 0.0f;
    if (gid < NNODES) {
        float a = h[gid * 75];                          // channel 0 = atomic number
        int tt = 5;                                     // catchall
        if      (a == 6.0f) tt = 0;
        else if (a == 7.0f) tt = 1;
        else if (a == 8.0f) tt = 2;
        else if (a == 9.0f) tt = 3;
        else if (a == 0.0f) tt = 4;
        int slot = atomicAdd(&counts[tt], 1);
        bucket[tt * NNODES + slot] = gid;
    }
}

// ---------------------------------------------------------------- MLP + aggregation
// One block per (node-half mh, bond kb, batch b). 64 nodes resident in LDS through
// all 8 layers; W staged in k-chunks of 32 (full 128 e-rows) -> 8x8 register tiles.
// Then m_part[n][d] = sum_m g[b,kb,n,m] * xb[m][d] for this block's 64 m-nodes,
// atomically accumulated into m_non (kb<6) or m_uni (kb==6).
__global__ __launch_bounds__(128) void mlp_agg_kernel(
    const float* __restrict__ hT, const float* __restrict__ msgW,
    const float* __restrict__ gmat, float* __restrict__ m_non, float* __restrict__ m_uni)
{
    __shared__ float act[64 * 132];   // [64 nodes][128 k], pitch 132 (16B-aligned, conflict-free)
    __shared__ float stg[128 * 36];   // W chunk [128 e][32 k] pitch 36  |  g tile [64 n][64 m] pitch 68

    const int t  = threadIdx.x;
    const int mh = blockIdx.x;        // node half (0/1)
    const int kb = blockIdx.y;        // bond type
    const int b  = blockIdx.z;        // batch
    const int i0 = mh * 64;

    // ---- stage activations (layer-0 input = h_t rows) ----
    {
        const float* src = hT + ((size_t)(b * 128 + i0)) * 128;
        #pragma unroll
        for (int q = t; q < 64 * 32; q += 128) {
            int row = q >> 5, c4 = q & 31;
            float4 v = *(const float4*)(src + row * 128 + c4 * 4);
            *(float4*)(act + row * 132 + c4 * 4) = v;
        }
    }
    __syncthreads();

    const int ig = t & 7;     // i = ig + 8*di  (strided: bank-conflict-free)
    const int eg = t >> 3;    // e = eg + 16*ee
    float acc[8][8];

    for (int l = 0; l < NLAY; ++l) {
        #pragma unroll
        for (int di = 0; di < 8; ++di)
            #pragma unroll
            for (int ee = 0; ee < 8; ++ee) acc[di][ee] = 0.0f;

        for (int kc = 0; kc < 4; ++kc) {
            // stage W k-chunk: rows = all 128 e, cols = k in [kc*32, kc*32+32)
            const float* wsrc = msgW + ((size_t)(kb * NLAY + l) * 128) * 128 + kc * 32;
            #pragma unroll
            for (int q = t; q < 128 * 8; q += 128) {
                int e = q >> 3, c4 = q & 7;
                float4 v = *(const float4*)(wsrc + e * 128 + c4 * 4);
                *(float4*)(stg + e * 36 + c4 * 4) = v;
            }
            __syncthreads();
            #pragma unroll
            for (int kk = 0; kk < 8; ++kk) {
                float4 a[8], w[8];
                #pragma unroll
                for (int di = 0; di < 8; ++di) {
                    int i = ig + 8 * di;
                    a[di] = *(const float4*)(act + i * 132 + (kc * 8 + kk) * 4);
                }
                #pragma unroll
                for (int ee = 0; ee < 8; ++ee) {
                    int e = eg + 16 * ee;
                    w[ee] = *(const float4*)(stg + e * 36 + kk * 4);
                }
                #pragma unroll
                for (int di = 0; di < 8; ++di)
                    #pragma unroll
                    for (int ee = 0; ee < 8; ++ee)
                        acc[di][ee] += a[di].x * w[ee].x + a[di].y * w[ee].y
                                     + a[di].z * w[ee].z + a[di].w * w[ee].w;
            }
            __syncthreads();
        }
        // write back (ReLU on all but last layer); all reads of old act are done.
        #pragma unroll
        for (int di = 0; di < 8; ++di) {
            int i = ig + 8 * di;
            #pragma unroll
            for (int ee = 0; ee < 8; ++ee) {
                int e = eg + 16 * ee;
                float v = acc[di][ee];
                if (l < NLAY - 1) v = fmaxf(v, 0.0f);
                act[i * 132 + e] = v;
            }
        }
        __syncthreads();
    }

    // ---- aggregation: m[n][d] += sum_ml g[n][i0+ml] * act[ml][d] ----
    const int dgl = t & 15;   // d = dgl + 16*dd  (lanes cover consecutive d -> coalesced atomics)
    const int ng  = t >> 4;   // n = ng + 8*ni (within n-half)
    float* dst = (kb == NBOND - 1) ? m_uni : m_non;

    for (int nh = 0; nh < 2; ++nh) {
        const float* gsrc = gmat + ((size_t)((b * NBOND + kb) * 128 + nh * 64)) * 128 + i0;
        #pragma unroll
        for (int q = t; q < 64 * 16; q += 128) {
            int nl = q >> 4, c4 = q & 15;
            float4 v = *(const float4*)(gsrc + nl * 128 + c4 * 4);
            *(float4*)(stg + nl * 68 + c4 * 4) = v;
        }
        __syncthreads();

        float acg[8][8];
        #pragma unroll
        for (int ni = 0; ni < 8; ++ni)
            #pragma unroll
            for (int dd = 0; dd < 8; ++dd) acg[ni][dd] = 0.0f;

        for (int ml = 0; ml < 64; ++ml) {
            float a[8];
            #pragma unroll
            for (int dd = 0; dd < 8; ++dd) a[dd] = act[ml * 132 + dgl + 16 * dd];
            #pragma unroll
            for (int ni = 0; ni < 8; ++ni) {
                float gv = stg[(ng + 8 * ni) * 68 + ml];
                #pragma unroll
                for (int dd = 0; dd < 8; ++dd) acg[ni][dd] += gv * a[dd];
            }
        }
        #pragma unroll
        for (int ni = 0; ni < 8; ++ni) {
            int n = nh * 64 + ng + 8 * ni;
            float* rowp = dst + ((size_t)(b * 128 + n)) * 128;
            #pragma unroll
            for (int dd = 0; dd < 8; ++dd)
                atomicAdd(rowp + dgl + 16 * dd, acg[ni][dd]);
        }
        __syncthreads();
    }
}

// ---------------------------------------------------------------- grouped GRU
// grid (chunk, type): 32 gathered nodes per block, both variants (regular m_non /
// universal m_uni), h_t updated in place: h_new = out0 + out1.
__global__ __launch_bounds__(256) void gru_kernel(
    float* __restrict__ hT, const float* __restrict__ m_non, const float* __restrict__ m_uni,
    const int* __restrict__ counts, const int* __restrict__ bucket,
    const float* __restrict__ Wih, const float* __restrict__ Whh,
    const float* __restrict__ bihp, const float* __restrict__ bhhp)
{
    __shared__ float X[32 * 132];   // gathered h rows
    __shared__ float M[32 * 132];   // gathered m rows (per variant)
    __shared__ float W[32 * 132];   // weight chunk [32 rows][128 k]

    const int t    = threadIdx.x;
    const int tt   = blockIdx.y;
    const int cnt  = counts[tt];
    const int base = blockIdx.x * 32;
    if (base >= cnt) return;                     // uniform early-exit
    const int nn = min(32, cnt - base);
    const int* blist = bucket + tt * NNODES + base;

    // stage X (zero-fill inactive rows)
    #pragma unroll
    for (int q = t; q < 32 * 32; q += 256) {
        int row = q >> 5, c4 = q & 31;
        float4 v = make_float4(0.f, 0.f, 0.f, 0.f);
        if (row < nn) {
            int node = blist[row];
            v = *(const float4*)(hT + (size_t)node * 128 + c4 * 4);
        }
        *(float4*)(X + row * 132 + c4 * 4) = v;
    }

    const int ih = t >> 4;   // i = 2*ih + di
    const int dl = t & 15;   // d = ch*32 + dl + 16*dd

    float hacc[2][8];
    #pragma unroll
    for (int di = 0; di < 2; ++di)
        #pragma unroll
        for (int j = 0; j < 8; ++j) hacc[di][j] = 0.0f;

    for (int v = 0; v < 2; ++v) {
        const float* msrc = v ? m_uni : m_non;
        __syncthreads();                         // X committed / previous-variant M reads done
        #pragma unroll
        for (int q = t; q < 32 * 32; q += 256) {
            int row = q >> 5, c4 = q & 31;
            float4 mv = make_float4(0.f, 0.f, 0.f, 0.f);
            if (row < nn) {
                int node = blist[row];
                mv = *(const float4*)(msrc + (size_t)node * 128 + c4 * 4);
            }
            *(float4*)(M + row * 132 + c4 * 4) = mv;
        }
        __syncthreads();

        float ar[2][8], az[2][8], ax[2][8], ah[2][8];
        #pragma unroll
        for (int di = 0; di < 2; ++di)
            #pragma unroll
            for (int j = 0; j < 8; ++j) { ar[di][j] = az[di][j] = ax[di][j] = ah[di][j] = 0.0f; }

        const size_t wbase = ((size_t)v * NTYPE + tt) * 384;

        #pragma unroll
        for (int gate = 0; gate < 3; ++gate) {
            #pragma unroll
            for (int mat = 0; mat < 2; ++mat) {
                const float* A = mat ? M : X;
                const float* wsrc0 = (mat ? Whh : Wih) + (wbase + gate * 128) * 128;
                #pragma unroll
                for (int ch = 0; ch < 4; ++ch) {
                    const float* wsrc = wsrc0 + (size_t)ch * 32 * 128;
                    #pragma unroll
                    for (int q = t; q < 32 * 32; q += 256) {
                        int row = q >> 5, c4 = q & 31;
                        float4 wv = *(const float4*)(wsrc + row * 128 + c4 * 4);
                        *(float4*)(W + row * 132 + c4 * 4) = wv;
                    }
                    __syncthreads();

                    float s[2][2] = {{0.f, 0.f}, {0.f, 0.f}};
                    for (int kc4 = 0; kc4 < 32; ++kc4) {
                        float4 a0 = *(const float4*)(A + (2 * ih + 0) * 132 + kc4 * 4);
                        float4 a1 = *(const float4*)(A + (2 * ih + 1) * 132 + kc4 * 4);
                        #pragma unroll
                        for (int dd = 0; dd < 2; ++dd) {
                            float4 wv = *(const float4*)(W + (dl + 16 * dd) * 132 + kc4 * 4);
                            s[0][dd] += a0.x * wv.x + a0.y * wv.y + a0.z * wv.z + a0.w * wv.w;
                            s[1][dd] += a1.x * wv.x + a1.y * wv.y + a1.z * wv.z + a1.w * wv.w;
                        }
                    }
                    #pragma unroll
                    for (int di = 0; di < 2; ++di)
                        #pragma unroll
                        for (int dd = 0; dd < 2; ++dd) {
                            int j = ch * 2 + dd;
                            float sv = s[di][dd];
                            if      (gate == 0) ar[di][j] += sv;
                            else if (gate == 1) az[di][j] += sv;
                            else if (mat == 0)  ax[di][j] += sv;
                            else                ah[di][j] += sv;
                        }
                    __syncthreads();
                }
            }
        }

        // nonlinearities + combine:  out = (1-z)*tanh(xn + r*hn) + z*m
        const float* bi = bihp + wbase;
        const float* bh = bhhp + wbase;
        #pragma unroll
        for (int j = 0; j < 8; ++j) {
            int d = (j >> 1) * 32 + dl + 16 * (j & 1);
            float br  = bi[d]       + bh[d];
            float bz  = bi[128 + d] + bh[128 + d];
            float bin = bi[256 + d];
            float bhn = bh[256 + d];
            #pragma unroll
            for (int di = 0; di < 2; ++di) {
                int i = 2 * ih + di;
                float r  = sig_(ar[di][j] + br);
                float z  = sig_(az[di][j] + bz);
                float nv = tanhf(ax[di][j] + bin + r * (ah[di][j] + bhn));
                float mv = M[i * 132 + d];
                hacc[di][j] += (1.0f - z) * nv + z * mv;
            }
        }
    }

    // scatter h_new
    #pragma unroll
    for (int di = 0; di < 2; ++di) {
        int i = 2 * ih + di;
        if (i < nn) {
            int node = blist[i];
            #pragma unroll
            for (int j = 0; j < 8; ++j) {
                int d = (j >> 1) * 32 + dl + 16 * (j & 1);
                hT[(size_t)node * 128 + d] = hacc[di][j];
            }
        }
    }
}

// ---------------------------------------------------------------- launch
extern "C" void kernel_launch(void* const* d_in, const int* in_sizes, int n_in,
                              void* d_out, int out_size, void* d_ws, size_t ws_size,
                              hipStream_t stream) {
    const float* g    = (const float*)d_in[0];
    const float* h    = (const float*)d_in[1];
    const float* msgW = (const float*)d_in[2];
    const float* Wih  = (const float*)d_in[3];
    const float* Whh  = (const float*)d_in[4];
    const float* bih  = (const float*)d_in[5];
    const float* bhh  = (const float*)d_in[6];
    float* hT = (float*)d_out;                       // h_t lives in d_out, updated in place

    char* ws = (char*)d_ws;
    float* m_non = (float*)ws;                       // [16384][128]
    float* m_uni = m_non + (size_t)NNODES * 128;     // [16384][128]
    int* counts  = (int*)(ws + 2 * (size_t)NNODES * 128 * 4);
    int* bucket  = counts + 8;                       // [6][16384]

    hipMemsetAsync(counts, 0, 8 * sizeof(int), stream);
    setup_kernel<<<NNODES * 128 / 256, 256, 0, stream>>>(h, hT, counts, bucket);

    for (int pass = 0; pass < 3; ++pass) {
        hipMemsetAsync(m_non, 0, 2 * (size_t)NNODES * 128 * 4, stream);
        mlp_agg_kernel<<<dim3(2, NBOND, 128), 128, 0, stream>>>(hT, msgW, g, m_non, m_uni);
        gru_kernel<<<dim3(512, NTYPE), 256, 0, stream>>>(hT, m_non, m_uni, counts, bucket,
                                                         Wih, Whh, bih, bhh);
    }
}

// Round 2
// 4884.752 us; speedup vs baseline: 8.8603x; 8.8603x over previous
//
#include <hip/hip_runtime.h>
#include <math.h>

#define NBOND 7
#define NLAY 8
#define NTYPE 6
#define NNODES 16384   // B*N = 128*128

__device__ __forceinline__ float sig_(float x) { return 1.0f / (1.0f + __expf(-x)); }

// ---------------------------------------------------------------- setup:
// h_t = concat(h, zeros) into d_out; bucket nodes by atom type (channel 0).
__global__ void setup_kernel(const float* __restrict__ h, float* __restrict__ hT,
                             int* __restrict__ counts, int* __restrict__ bucket)
{
    int gid = blockIdx.x * 256 + threadIdx.x;
    int node = gid >> 7, d = gid & 127;
    hT[gid] = (d < 75) ? h[node * 75 + d] : 0.0f;
    if (gid < NNODES) {
        float a = h[gid * 75];
        int tt = 5;
        if      (a == 6.0f) tt = 0;
        else if (a == 7.0f) tt = 1;
        else if (a == 8.0f) tt = 2;
        else if (a == 9.0f) tt = 3;
        else if (a == 0.0f) tt = 4;
        int slot = atomicAdd(&counts[tt], 1);
        bucket[tt * NNODES + slot] = gid;
    }
}

// ---------------------------------------------------------------- MLP + aggregation
// Block = 256 threads, one per (node-half mh, bond kb, batch b).
// 64 nodes resident in LDS through 8 layers; per-thread tile 4 nodes x 8 cols
// (32 acc regs -> no spill; 12 ds_read_b128 per kk vs 256 VALU-cyc -> VALU-bound).
__global__ __launch_bounds__(256) void mlp_agg_kernel(
    const float* __restrict__ hT, const float* __restrict__ msgW,
    const float* __restrict__ gmat, float* __restrict__ m_non, float* __restrict__ m_uni)
{
    __shared__ float act[64 * 132];   // [64 nodes][128 k] pitch 132
    __shared__ float stg[128 * 36];   // W chunk [128 e][32 k] pitch 36 | g tile [64 n][64 m] pitch 68

    const int t  = threadIdx.x;
    const int mh = blockIdx.x;
    const int kb = blockIdx.y;
    const int b  = blockIdx.z;
    const int i0 = mh * 64;

    // stage layer-0 activations
    {
        const float* src = hT + ((size_t)(b * 128 + i0)) * 128;
        #pragma unroll
        for (int q = t; q < 64 * 32; q += 256) {
            int row = q >> 5, c4 = q & 31;
            *(float4*)(act + row * 132 + c4 * 4) = *(const float4*)(src + row * 128 + c4 * 4);
        }
    }
    __syncthreads();

    const int ig = t & 15;    // i = ig + 16*di (di 0..3)
    const int eg = t >> 4;    // e = eg + 16*ee (ee 0..7)
    float acc[4][8];

    #pragma unroll 1
    for (int l = 0; l < NLAY; ++l) {
        #pragma unroll
        for (int di = 0; di < 4; ++di)
            #pragma unroll
            for (int ee = 0; ee < 8; ++ee) acc[di][ee] = 0.0f;

        #pragma unroll 1
        for (int kc = 0; kc < 4; ++kc) {
            const float* wsrc = msgW + ((size_t)(kb * NLAY + l) * 128) * 128 + kc * 32;
            #pragma unroll
            for (int q = t; q < 128 * 8; q += 256) {
                int e = q >> 3, c4 = q & 7;
                *(float4*)(stg + e * 36 + c4 * 4) = *(const float4*)(wsrc + e * 128 + c4 * 4);
            }
            __syncthreads();
            #pragma unroll
            for (int kk = 0; kk < 8; ++kk) {
                float4 a[4], w[8];
                #pragma unroll
                for (int di = 0; di < 4; ++di)
                    a[di] = *(const float4*)(act + (ig + 16 * di) * 132 + (kc * 8 + kk) * 4);
                #pragma unroll
                for (int ee = 0; ee < 8; ++ee)
                    w[ee] = *(const float4*)(stg + (eg + 16 * ee) * 36 + kk * 4);
                #pragma unroll
                for (int di = 0; di < 4; ++di)
                    #pragma unroll
                    for (int ee = 0; ee < 8; ++ee)
                        acc[di][ee] += a[di].x * w[ee].x + a[di].y * w[ee].y
                                     + a[di].z * w[ee].z + a[di].w * w[ee].w;
            }
            __syncthreads();
        }
        #pragma unroll
        for (int di = 0; di < 4; ++di) {
            int i = ig + 16 * di;
            #pragma unroll
            for (int ee = 0; ee < 8; ++ee) {
                float v = acc[di][ee];
                if (l < NLAY - 1) v = fmaxf(v, 0.0f);
                act[i * 132 + eg + 16 * ee] = v;
            }
        }
        __syncthreads();
    }

    // aggregation: m[n][d] += sum_ml g[b,kb,n,i0+ml] * act[ml][d]
    const int dgl = t & 15;   // d = dgl + 16*dd (dd 0..7)
    const int ngg = t >> 4;   // n = ngg + 16*nj (nj 0..3) within n-half
    float* dst = (kb == NBOND - 1) ? m_uni : m_non;

    #pragma unroll 1
    for (int nh = 0; nh < 2; ++nh) {
        __syncthreads();   // protect stg from previous readers
        const float* gsrc = gmat + ((size_t)((b * NBOND + kb) * 128 + nh * 64)) * 128 + i0;
        #pragma unroll
        for (int q = t; q < 64 * 16; q += 256) {
            int nl = q >> 4, c4 = q & 15;
            *(float4*)(stg + nl * 68 + c4 * 4) = *(const float4*)(gsrc + nl * 128 + c4 * 4);
        }
        __syncthreads();

        float acg[4][8];
        #pragma unroll
        for (int nj = 0; nj < 4; ++nj)
            #pragma unroll
            for (int dd = 0; dd < 8; ++dd) acg[nj][dd] = 0.0f;

        #pragma unroll 2
        for (int ml = 0; ml < 64; ++ml) {
            float a[8];
            #pragma unroll
            for (int dd = 0; dd < 8; ++dd) a[dd] = act[ml * 132 + dgl + 16 * dd];
            #pragma unroll
            for (int nj = 0; nj < 4; ++nj) {
                float gv = stg[(ngg + 16 * nj) * 68 + ml];
                #pragma unroll
                for (int dd = 0; dd < 8; ++dd) acg[nj][dd] += gv * a[dd];
            }
        }
        #pragma unroll
        for (int nj = 0; nj < 4; ++nj) {
            int n = nh * 64 + ngg + 16 * nj;
            float* rowp = dst + ((size_t)(b * 128 + n)) * 128;
            #pragma unroll
            for (int dd = 0; dd < 8; ++dd)
                atomicAdd(rowp + dgl + 16 * dd, acg[nj][dd]);
        }
    }
}

// ---------------------------------------------------------------- grouped GRU
// Block = 256 threads, 32 gathered nodes of one type; both variants accumulated.
// Phase-ordered gates (r -> n -> z) keep peak live accumulators ~48.
__device__ __forceinline__ void gru_gemm(float (&acc)[2][8], const float* __restrict__ Al,
                                         const float* __restrict__ wg, float* Wl,
                                         int t, int ih, int dl)
{
    #pragma unroll
    for (int ch = 0; ch < 2; ++ch) {
        #pragma unroll 1
        for (int kc = 0; kc < 4; ++kc) {
            __syncthreads();   // previous Wl readers done
            #pragma unroll
            for (int q = t; q < 512; q += 256) {
                int row = q >> 3, c4 = q & 7;
                *(float4*)(Wl + row * 36 + c4 * 4) =
                    *(const float4*)(wg + (size_t)(ch * 64 + row) * 128 + kc * 32 + c4 * 4);
            }
            __syncthreads();
            #pragma unroll
            for (int k4 = 0; k4 < 8; ++k4) {
                float4 a0 = *(const float4*)(Al + (2 * ih + 0) * 132 + kc * 32 + k4 * 4);
                float4 a1 = *(const float4*)(Al + (2 * ih + 1) * 132 + kc * 32 + k4 * 4);
                #pragma unroll
                for (int dd = 0; dd < 4; ++dd) {
                    float4 w = *(const float4*)(Wl + (dl + 16 * dd) * 36 + k4 * 4);
                    acc[0][ch * 4 + dd] += a0.x * w.x + a0.y * w.y + a0.z * w.z + a0.w * w.w;
                    acc[1][ch * 4 + dd] += a1.x * w.x + a1.y * w.y + a1.z * w.z + a1.w * w.w;
                }
            }
        }
    }
}

__global__ __launch_bounds__(256) void gru_kernel(
    float* __restrict__ hT, const float* __restrict__ m_non, const float* __restrict__ m_uni,
    const int* __restrict__ counts, const int* __restrict__ bucket,
    const float* __restrict__ Wih, const float* __restrict__ Whh,
    const float* __restrict__ bihp, const float* __restrict__ bhhp)
{
    __shared__ float X[32 * 132];
    __shared__ float M[32 * 132];
    __shared__ float W[64 * 36];

    const int t    = threadIdx.x;
    const int tt   = blockIdx.y;
    const int cnt  = counts[tt];
    const int base = blockIdx.x * 32;
    if (base >= cnt) return;
    const int nn = min(32, cnt - base);
    const int* blist = bucket + tt * NNODES + base;

    // stage X (gathered h rows, zero-fill inactive)
    #pragma unroll
    for (int q = t; q < 32 * 32; q += 256) {
        int row = q >> 5, c4 = q & 31;
        float4 v = make_float4(0.f, 0.f, 0.f, 0.f);
        if (row < nn) v = *(const float4*)(hT + (size_t)blist[row] * 128 + c4 * 4);
        *(float4*)(X + row * 132 + c4 * 4) = v;
    }

    const int ih = t >> 4;   // nodes 2*ih, 2*ih+1
    const int dl = t & 15;   // col = ch*64 + dl + 16*dd

    float hacc[2][8];
    #pragma unroll
    for (int di = 0; di < 2; ++di)
        #pragma unroll
        for (int j = 0; j < 8; ++j) hacc[di][j] = 0.0f;

    #pragma unroll 1
    for (int v = 0; v < 2; ++v) {
        const float* msrc = v ? m_uni : m_non;
        __syncthreads();   // previous-variant M readers done (also X-stage commit)
        #pragma unroll
        for (int q = t; q < 32 * 32; q += 256) {
            int row = q >> 5, c4 = q & 31;
            float4 mv = make_float4(0.f, 0.f, 0.f, 0.f);
            if (row < nn) mv = *(const float4*)(msrc + (size_t)blist[row] * 128 + c4 * 4);
            *(float4*)(M + row * 132 + c4 * 4) = mv;
        }
        // visibility guaranteed by the sync inside gru_gemm before first compute

        const size_t wbase = ((size_t)v * NTYPE + tt) * 384;
        const float* wih = Wih + wbase * 128;
        const float* whh = Whh + wbase * 128;
        const float* bi = bihp + wbase;
        const float* bh = bhhp + wbase;

        // ---- gate r ----
        float ar[2][8];
        #pragma unroll
        for (int di = 0; di < 2; ++di)
            #pragma unroll
            for (int j = 0; j < 8; ++j) ar[di][j] = 0.0f;
        gru_gemm(ar, X, wih, W, t, ih, dl);             // x @ Wih_r
        gru_gemm(ar, M, whh, W, t, ih, dl);             // m @ Whh_r
        #pragma unroll
        for (int j = 0; j < 8; ++j) {
            int d = (j >> 2) * 64 + dl + 16 * (j & 3);
            float br = bi[d] + bh[d];
            ar[0][j] = sig_(ar[0][j] + br);
            ar[1][j] = sig_(ar[1][j] + br);
        }

        // ---- gate n ----
        float axn[2][8], ahn[2][8];
        #pragma unroll
        for (int di = 0; di < 2; ++di)
            #pragma unroll
            for (int j = 0; j < 8; ++j) { axn[di][j] = 0.0f; ahn[di][j] = 0.0f; }
        gru_gemm(axn, X, wih + (size_t)256 * 128, W, t, ih, dl);
        gru_gemm(ahn, M, whh + (size_t)256 * 128, W, t, ih, dl);
        #pragma unroll
        for (int j = 0; j < 8; ++j) {
            int d = (j >> 2) * 64 + dl + 16 * (j & 3);
            float bin = bi[256 + d], bhn = bh[256 + d];
            #pragma unroll
            for (int di = 0; di < 2; ++di)
                axn[di][j] = tanhf(axn[di][j] + bin + ar[di][j] * (ahn[di][j] + bhn));
        }

        // ---- gate z + combine ----
        float az[2][8];
        #pragma unroll
        for (int di = 0; di < 2; ++di)
            #pragma unroll
            for (int j = 0; j < 8; ++j) az[di][j] = 0.0f;
        gru_gemm(az, X, wih + (size_t)128 * 128, W, t, ih, dl);
        gru_gemm(az, M, whh + (size_t)128 * 128, W, t, ih, dl);
        __syncthreads();   // last Wl compute done; M reads below are safe anyway
        #pragma unroll
        for (int j = 0; j < 8; ++j) {
            int d = (j >> 2) * 64 + dl + 16 * (j & 3);
            float bz = bi[128 + d] + bh[128 + d];
            #pragma unroll
            for (int di = 0; di < 2; ++di) {
                float z = sig_(az[di][j] + bz);
                float mv = M[(2 * ih + di) * 132 + d];
                hacc[di][j] += (1.0f - z) * axn[di][j] + z * mv;
            }
        }
    }

    // scatter h_new
    #pragma unroll
    for (int di = 0; di < 2; ++di) {
        int i = 2 * ih + di;
        if (i < nn) {
            int node = blist[i];
            #pragma unroll
            for (int j = 0; j < 8; ++j) {
                int d = (j >> 2) * 64 + dl + 16 * (j & 3);
                hT[(size_t)node * 128 + d] = hacc[di][j];
            }
        }
    }
}

// ---------------------------------------------------------------- launch
extern "C" void kernel_launch(void* const* d_in, const int* in_sizes, int n_in,
                              void* d_out, int out_size, void* d_ws, size_t ws_size,
                              hipStream_t stream) {
    const float* g    = (const float*)d_in[0];
    const float* h    = (const float*)d_in[1];
    const float* msgW = (const float*)d_in[2];
    const float* Wih  = (const float*)d_in[3];
    const float* Whh  = (const float*)d_in[4];
    const float* bih  = (const float*)d_in[5];
    const float* bhh  = (const float*)d_in[6];
    float* hT = (float*)d_out;

    char* ws = (char*)d_ws;
    float* m_non = (float*)ws;                       // [16384][128]
    float* m_uni = m_non + (size_t)NNODES * 128;     // [16384][128]
    int* counts  = (int*)(ws + 2 * (size_t)NNODES * 128 * 4);
    int* bucket  = counts + 8;                       // [6][16384]

    hipMemsetAsync(counts, 0, 8 * sizeof(int), stream);
    setup_kernel<<<NNODES * 128 / 256, 256, 0, stream>>>(h, hT, counts, bucket);

    for (int pass = 0; pass < 3; ++pass) {
        hipMemsetAsync(m_non, 0, 2 * (size_t)NNODES * 128 * 4, stream);
        mlp_agg_kernel<<<dim3(2, NBOND, 128), 256, 0, stream>>>(hT, msgW, g, m_non, m_uni);
        gru_kernel<<<dim3(512, NTYPE), 256, 0, stream>>>(hT, m_non, m_uni, counts, bucket,
                                                         Wih, Whh, bih, bhh);
    }
}

// Round 5
// 953.199 us; speedup vs baseline: 45.4056x; 5.1246x over previous
//
#include <hip/hip_runtime.h>
#include <math.h>

#define NBOND 7
#define NLAY 8
#define NTYPE 6
#define NNODES 16384   // B*N = 128*128
#define PX 136         // LDS pitch in halves (272 B, 16B-aligned; 68 dw % 32 = 4 -> conflict-clean)

typedef _Float16 half8 __attribute__((ext_vector_type(8)));
typedef _Float16 half4 __attribute__((ext_vector_type(4)));
typedef float floatx16 __attribute__((ext_vector_type(16)));

__device__ __forceinline__ float sig_(float x) { return 1.0f / (1.0f + __expf(-x)); }
// D-layout for 32x32 MFMA: col = lane&31, row = (reg&3) + 8*(reg>>2) + 4*(lane>>5)
__device__ __forceinline__ int drow_(int reg, int hi) { return (reg & 3) + 8 * (reg >> 2) + 4 * hi; }

__device__ __forceinline__ _Float16 hi_(float v) { return (_Float16)v; }
__device__ __forceinline__ _Float16 lo_(float v) { return (_Float16)(v - (float)(_Float16)v); }

// ---------------------------------------------------------------- setup
__global__ void setup_kernel(const float* __restrict__ h, float* __restrict__ hT,
                             int* __restrict__ counts, int* __restrict__ bucket)
{
    int gid = blockIdx.x * 256 + threadIdx.x;
    int node = gid >> 7, d = gid & 127;
    hT[gid] = (d < 75) ? h[node * 75 + d] : 0.0f;
    if (gid < NNODES) {
        float a = h[gid * 75];
        int tt = 5;
        if      (a == 6.0f) tt = 0;
        else if (a == 7.0f) tt = 1;
        else if (a == 8.0f) tt = 2;
        else if (a == 9.0f) tt = 3;
        else if (a == 0.0f) tt = 4;
        int slot = atomicAdd(&counts[tt], 1);
        bucket[tt * NNODES + slot] = gid;
    }
}

// ---------------------------------------------------------------- weight packing (fp32 -> split fp16 hi/lo planes)
// msgW: [(kb*8+l)][c 0..15][plane hi/lo][e 0..127][j 0..7]  (j along input dim d)
__global__ void pack_msg_kernel(const float* __restrict__ msgW, _Float16* __restrict__ Wp)
{
    int idx = blockIdx.x * 256 + threadIdx.x;
    if (idx >= NBOND * NLAY * 16 * 128) return;
    int e  = idx & 127;
    int c  = (idx >> 7) & 15;
    int kl = idx >> 11;
    const float* src = msgW + ((size_t)kl * 128 + e) * 128 + c * 8;
    float4 u = *(const float4*)src;
    float4 v = *(const float4*)(src + 4);
    float av[8] = {u.x, u.y, u.z, u.w, v.x, v.y, v.z, v.w};
    half8 hh, ll;
    #pragma unroll
    for (int j = 0; j < 8; ++j) { hh[j] = hi_(av[j]); ll[j] = lo_(av[j]); }
    _Float16* dst = Wp + ((size_t)kl * 16 + c) * 2048;
    *(half8*)(dst + e * 8)        = hh;
    *(half8*)(dst + 1024 + e * 8) = ll;
}

// GRU: [(vt*2+mat)][c 0..15][plane hi/lo][col 0..383][j 0..7]
__global__ void pack_gru_kernel(const float* __restrict__ Wih, const float* __restrict__ Whh,
                                _Float16* __restrict__ Wp)
{
    int idx = blockIdx.x * 256 + threadIdx.x;
    if (idx >= 2 * NTYPE * 2 * 16 * 384) return;
    int col = idx % 384;
    int c   = (idx / 384) & 15;
    int vm  = idx / 6144;       // (vt*2 + mat), vt = v*6+tt
    int mat = vm & 1;
    int vt  = vm >> 1;
    const float* src = (mat ? Whh : Wih) + ((size_t)vt * 384 + col) * 128 + c * 8;
    float4 u = *(const float4*)src;
    float4 v = *(const float4*)(src + 4);
    float av[8] = {u.x, u.y, u.z, u.w, v.x, v.y, v.z, v.w};
    half8 hh, ll;
    #pragma unroll
    for (int j = 0; j < 8; ++j) { hh[j] = hi_(av[j]); ll[j] = lo_(av[j]); }
    _Float16* dst = Wp + (size_t)vm * 98304 + (size_t)c * 6144;
    *(half8*)(dst + col * 8)        = hh;
    *(half8*)(dst + 3072 + col * 8) = ll;
}

// ---------------------------------------------------------------- MLP + aggregation (split-fp16 MFMA)
// One block per (kb, b): 128 nodes resident in LDS (hi/lo planes) through 8 layers.
// Wave w owns row-tile w (rows w*32..+31) and ALL 4 col-tiles: A-frag reused 4x
// -> LDS traffic 2 KB per 12 MFMA (under the 128 B/cyc budget). B direct from L2.
__global__ __launch_bounds__(256) void mlp_agg_mfma(
    const float* __restrict__ hT, const _Float16* __restrict__ Wp,
    const float* __restrict__ gmat, float* __restrict__ m_non, float* __restrict__ m_uni)
{
    __shared__ _Float16 Xhi[128 * PX];
    __shared__ _Float16 Xlo[128 * PX];

    const int t = threadIdx.x;
    const int kb = blockIdx.x, b = blockIdx.y;
    const int wave = t >> 6, lane = t & 63, lo = lane & 31, hi = lane >> 5;
    const int row = wave * 32 + lo;   // A-operand row for this lane

    // stage layer-0 activations (fp32 -> hi/lo fp16)
    for (int q = t; q < 128 * 32; q += 256) {
        int r = q >> 5, c4 = q & 31;
        float4 v = *(const float4*)(hT + ((size_t)(b * 128 + r)) * 128 + c4 * 4);
        half4 hh, ll;
        hh[0] = hi_(v.x); ll[0] = lo_(v.x);
        hh[1] = hi_(v.y); ll[1] = lo_(v.y);
        hh[2] = hi_(v.z); ll[2] = lo_(v.z);
        hh[3] = hi_(v.w); ll[3] = lo_(v.w);
        *(half4*)(Xhi + r * PX + c4 * 4) = hh;
        *(half4*)(Xlo + r * PX + c4 * 4) = ll;
    }
    __syncthreads();

    floatx16 acc[4];

    #pragma unroll 1
    for (int l = 0; l < NLAY; ++l) {
        #pragma unroll
        for (int ct = 0; ct < 4; ++ct) acc[ct] = (floatx16)0.0f;
        const _Float16* wb = Wp + ((size_t)(kb * NLAY + l) * 16) * 2048;

        #pragma unroll 2
        for (int kk = 0; kk < 8; ++kk) {
            half8 a_h = *(const half8*)(Xhi + row * PX + kk * 16 + hi * 8);
            half8 a_l = *(const half8*)(Xlo + row * PX + kk * 16 + hi * 8);
            const _Float16* bp = wb + (size_t)(kk * 2 + hi) * 2048;
            #pragma unroll
            for (int ct = 0; ct < 4; ++ct) {
                half8 b_h = *(const half8*)(bp + (ct * 32 + lo) * 8);
                half8 b_l = *(const half8*)(bp + 1024 + (ct * 32 + lo) * 8);
                acc[ct] = __builtin_amdgcn_mfma_f32_32x32x16_f16(a_h, b_h, acc[ct], 0, 0, 0);
                acc[ct] = __builtin_amdgcn_mfma_f32_32x32x16_f16(a_h, b_l, acc[ct], 0, 0, 0);
                acc[ct] = __builtin_amdgcn_mfma_f32_32x32x16_f16(a_l, b_h, acc[ct], 0, 0, 0);
            }
        }
        __syncthreads();   // all X reads for this layer done

        if (l < NLAY - 1) {
            #pragma unroll
            for (int ct = 0; ct < 4; ++ct)
                #pragma unroll
                for (int reg = 0; reg < 16; ++reg) {
                    int n = wave * 32 + drow_(reg, hi);
                    float vv = fmaxf(acc[ct][reg], 0.0f);
                    Xhi[n * PX + ct * 32 + lo] = hi_(vv);
                    Xlo[n * PX + ct * 32 + lo] = lo_(vv);
                }
        } else {
            // final layer: store transposed Xt[e][m] so agg B-frags are contiguous
            #pragma unroll
            for (int ct = 0; ct < 4; ++ct)
                #pragma unroll
                for (int s = 0; s < 4; ++s) {
                    int e = ct * 32 + lo, m0 = wave * 32 + 8 * s + 4 * hi;
                    half4 hh, ll;
                    #pragma unroll
                    for (int j = 0; j < 4; ++j) {
                        float vv = acc[ct][4 * s + j];
                        hh[j] = hi_(vv); ll[j] = lo_(vv);
                    }
                    *(half4*)(Xhi + e * PX + m0) = hh;
                    *(half4*)(Xlo + e * PX + m0) = ll;
                }
        }
        __syncthreads();
    }

    // ---- aggregation: m[n][d] = sum_m g[b,kb,n,m]*xb[m][d];  A = g (inline split), B = Xt ----
    #pragma unroll
    for (int ct = 0; ct < 4; ++ct) acc[ct] = (floatx16)0.0f;
    const float* grow = gmat + (size_t)(b * NBOND + kb) * 16384;

    #pragma unroll 2
    for (int kk = 0; kk < 8; ++kk) {
        const float* gp = grow + (size_t)row * 128 + kk * 16 + hi * 8;
        float4 u = *(const float4*)gp, v2 = *(const float4*)(gp + 4);
        float av[8] = {u.x, u.y, u.z, u.w, v2.x, v2.y, v2.z, v2.w};
        half8 a_h, a_l;
        #pragma unroll
        for (int j = 0; j < 8; ++j) { a_h[j] = hi_(av[j]); a_l[j] = lo_(av[j]); }
        #pragma unroll
        for (int ct = 0; ct < 4; ++ct) {
            half8 b_h = *(const half8*)(Xhi + (ct * 32 + lo) * PX + kk * 16 + hi * 8);
            half8 b_l = *(const half8*)(Xlo + (ct * 32 + lo) * PX + kk * 16 + hi * 8);
            acc[ct] = __builtin_amdgcn_mfma_f32_32x32x16_f16(a_h, b_h, acc[ct], 0, 0, 0);
            acc[ct] = __builtin_amdgcn_mfma_f32_32x32x16_f16(a_h, b_l, acc[ct], 0, 0, 0);
            acc[ct] = __builtin_amdgcn_mfma_f32_32x32x16_f16(a_l, b_h, acc[ct], 0, 0, 0);
        }
    }

    if (kb == NBOND - 1) {
        #pragma unroll
        for (int ct = 0; ct < 4; ++ct)
            #pragma unroll
            for (int reg = 0; reg < 16; ++reg) {
                int n = wave * 32 + drow_(reg, hi);
                m_uni[((size_t)(b * 128 + n)) * 128 + ct * 32 + lo] = acc[ct][reg];
            }
    } else {
        #pragma unroll
        for (int ct = 0; ct < 4; ++ct)
            #pragma unroll
            for (int reg = 0; reg < 16; ++reg) {
                int n = wave * 32 + drow_(reg, hi);
                atomicAdd(m_non + ((size_t)(b * 128 + n)) * 128 + ct * 32 + lo, acc[ct][reg]);
            }
    }
}

// ---------------------------------------------------------------- grouped GRU (split-fp16 MFMA)
// Block = 64 gathered nodes of one type; wave w owns d in [w*32, w*32+32).
// rt outer (unroll 1, hacc static 16 regs), variant inner with Ms restaged.
__global__ __launch_bounds__(256) void gru_mfma(
    float* __restrict__ hT, const float* __restrict__ m_non, const float* __restrict__ m_uni,
    const int* __restrict__ counts, const int* __restrict__ bucket,
    const _Float16* __restrict__ Wp, const float* __restrict__ bihp, const float* __restrict__ bhhp)
{
    __shared__ _Float16 Xh[64 * PX], Xl[64 * PX], Mh[64 * PX], Ml[64 * PX];
    __shared__ int bl[64];

    const int t = threadIdx.x, tt = blockIdx.y;
    const int cnt  = counts[tt];
    const int base = blockIdx.x * 64;
    if (base >= cnt) return;
    const int nn = min(64, cnt - base);
    if (t < 64) bl[t] = (t < nn) ? bucket[tt * NNODES + base + t] : -1;
    __syncthreads();

    const int wave = t >> 6, lane = t & 63, lo = lane & 31, hi = lane >> 5;
    const int d = wave * 32 + lo;

    // stage X (gathered h rows, split fp16, zero-fill inactive)
    for (int q = t; q < 64 * 32; q += 256) {
        int r = q >> 5, c4 = q & 31;
        float4 v = make_float4(0.f, 0.f, 0.f, 0.f);
        int node = bl[r];
        if (node >= 0) v = *(const float4*)(hT + (size_t)node * 128 + c4 * 4);
        half4 hh, ll;
        hh[0] = hi_(v.x); ll[0] = lo_(v.x);
        hh[1] = hi_(v.y); ll[1] = lo_(v.y);
        hh[2] = hi_(v.z); ll[2] = lo_(v.z);
        hh[3] = hi_(v.w); ll[3] = lo_(v.w);
        *(half4*)(Xh + r * PX + c4 * 4) = hh;
        *(half4*)(Xl + r * PX + c4 * 4) = ll;
    }

    #pragma unroll 1
    for (int rt = 0; rt < 2; ++rt) {
        float hacc[16];
        #pragma unroll
        for (int reg = 0; reg < 16; ++reg) hacc[reg] = 0.0f;
        const int rrow = rt * 32 + lo;

        #pragma unroll 1
        for (int v = 0; v < 2; ++v) {
            const float* msrc = v ? m_uni : m_non;
            __syncthreads();   // previous Ms readers done (also covers X-stage commit)
            for (int q = t; q < 64 * 32; q += 256) {
                int r = q >> 5, c4 = q & 31;
                float4 mv = make_float4(0.f, 0.f, 0.f, 0.f);
                int node = bl[r];
                if (node >= 0) mv = *(const float4*)(msrc + (size_t)node * 128 + c4 * 4);
                half4 hh, ll;
                hh[0] = hi_(mv.x); ll[0] = lo_(mv.x);
                hh[1] = hi_(mv.y); ll[1] = lo_(mv.y);
                hh[2] = hi_(mv.z); ll[2] = lo_(mv.z);
                hh[3] = hi_(mv.w); ll[3] = lo_(mv.w);
                *(half4*)(Mh + r * PX + c4 * 4) = hh;
                *(half4*)(Ml + r * PX + c4 * 4) = ll;
            }
            __syncthreads();

            const int vt = v * NTYPE + tt;
            const _Float16* pih = Wp + (size_t)(vt * 2 + 0) * 98304;
            const _Float16* phh = Wp + (size_t)(vt * 2 + 1) * 98304;

            floatx16 ar = (floatx16)0.0f, az = (floatx16)0.0f;
            floatx16 ax = (floatx16)0.0f, ah = (floatx16)0.0f;

            #pragma unroll 2
            for (int kk = 0; kk < 8; ++kk) {
                int koff = kk * 16 + hi * 8;
                half8 xh = *(const half8*)(Xh + rrow * PX + koff);
                half8 xl = *(const half8*)(Xl + rrow * PX + koff);
                half8 mh = *(const half8*)(Mh + rrow * PX + koff);
                half8 ml = *(const half8*)(Ml + rrow * PX + koff);
                const _Float16* ci = pih + (size_t)(kk * 2 + hi) * 6144;
                const _Float16* ch = phh + (size_t)(kk * 2 + hi) * 6144;
                half8 birh = *(const half8*)(ci + (0   + d) * 8);
                half8 birl = *(const half8*)(ci + 3072 + (0   + d) * 8);
                half8 bizh = *(const half8*)(ci + (128 + d) * 8);
                half8 bizl = *(const half8*)(ci + 3072 + (128 + d) * 8);
                half8 binh = *(const half8*)(ci + (256 + d) * 8);
                half8 binl = *(const half8*)(ci + 3072 + (256 + d) * 8);
                half8 bhrh = *(const half8*)(ch + (0   + d) * 8);
                half8 bhrl = *(const half8*)(ch + 3072 + (0   + d) * 8);
                half8 bhzh = *(const half8*)(ch + (128 + d) * 8);
                half8 bhzl = *(const half8*)(ch + 3072 + (128 + d) * 8);
                half8 bhnh = *(const half8*)(ch + (256 + d) * 8);
                half8 bhnl = *(const half8*)(ch + 3072 + (256 + d) * 8);

                ar = __builtin_amdgcn_mfma_f32_32x32x16_f16(xh, birh, ar, 0, 0, 0);
                ar = __builtin_amdgcn_mfma_f32_32x32x16_f16(xh, birl, ar, 0, 0, 0);
                ar = __builtin_amdgcn_mfma_f32_32x32x16_f16(xl, birh, ar, 0, 0, 0);
                ar = __builtin_amdgcn_mfma_f32_32x32x16_f16(mh, bhrh, ar, 0, 0, 0);
                ar = __builtin_amdgcn_mfma_f32_32x32x16_f16(mh, bhrl, ar, 0, 0, 0);
                ar = __builtin_amdgcn_mfma_f32_32x32x16_f16(ml, bhrh, ar, 0, 0, 0);

                az = __builtin_amdgcn_mfma_f32_32x32x16_f16(xh, bizh, az, 0, 0, 0);
                az = __builtin_amdgcn_mfma_f32_32x32x16_f16(xh, bizl, az, 0, 0, 0);
                az = __builtin_amdgcn_mfma_f32_32x32x16_f16(xl, bizh, az, 0, 0, 0);
                az = __builtin_amdgcn_mfma_f32_32x32x16_f16(mh, bhzh, az, 0, 0, 0);
                az = __builtin_amdgcn_mfma_f32_32x32x16_f16(mh, bhzl, az, 0, 0, 0);
                az = __builtin_amdgcn_mfma_f32_32x32x16_f16(ml, bhzh, az, 0, 0, 0);

                ax = __builtin_amdgcn_mfma_f32_32x32x16_f16(xh, binh, ax, 0, 0, 0);
                ax = __builtin_amdgcn_mfma_f32_32x32x16_f16(xh, binl, ax, 0, 0, 0);
                ax = __builtin_amdgcn_mfma_f32_32x32x16_f16(xl, binh, ax, 0, 0, 0);
                ah = __builtin_amdgcn_mfma_f32_32x32x16_f16(mh, bhnh, ah, 0, 0, 0);
                ah = __builtin_amdgcn_mfma_f32_32x32x16_f16(mh, bhnl, ah, 0, 0, 0);
                ah = __builtin_amdgcn_mfma_f32_32x32x16_f16(ml, bhnh, ah, 0, 0, 0);
            }

            const float* bi = bihp + (size_t)vt * 384;
            const float* bh = bhhp + (size_t)vt * 384;
            float b_r  = bi[d] + bh[d];
            float b_z  = bi[128 + d] + bh[128 + d];
            float b_in = bi[256 + d];
            float b_hn = bh[256 + d];
            #pragma unroll
            for (int reg = 0; reg < 16; ++reg) {
                int n = rt * 32 + drow_(reg, hi);
                int node = bl[n];
                float r  = sig_(ar[reg] + b_r);
                float z  = sig_(az[reg] + b_z);
                float nv = tanhf(ax[reg] + b_in + r * (ah[reg] + b_hn));
                float mv = (node >= 0) ? msrc[(size_t)node * 128 + d] : 0.0f;   // fp32 m for z*m
                hacc[reg] += (1.0f - z) * nv + z * mv;
            }
        }

        // scatter h_new for this rt (coalesced along d)
        #pragma unroll
        for (int reg = 0; reg < 16; ++reg) {
            int n = rt * 32 + drow_(reg, hi);
            int node = bl[n];
            if (node >= 0) hT[(size_t)node * 128 + d] = hacc[reg];
        }
    }
}

// ---------------------------------------------------------------- launch
extern "C" void kernel_launch(void* const* d_in, const int* in_sizes, int n_in,
                              void* d_out, int out_size, void* d_ws, size_t ws_size,
                              hipStream_t stream) {
    const float* g    = (const float*)d_in[0];
    const float* h    = (const float*)d_in[1];
    const float* msgW = (const float*)d_in[2];
    const float* Wih  = (const float*)d_in[3];
    const float* Whh  = (const float*)d_in[4];
    const float* bih  = (const float*)d_in[5];
    const float* bhh  = (const float*)d_in[6];
    float* hT = (float*)d_out;

    char* ws = (char*)d_ws;
    float* m_non = (float*)ws;                                   // 8 MB
    float* m_uni = m_non + (size_t)NNODES * 128;                 // 8 MB
    int* counts  = (int*)(ws + 2 * (size_t)NNODES * 128 * 4);
    int* bucket  = counts + 8;                                   // [6][16384]
    _Float16* WpM = (_Float16*)(bucket + NTYPE * NNODES);        // 1,835,008 halves (3.67 MB)
    _Float16* WpG = WpM + (size_t)NBOND * NLAY * 16 * 2048;      // 2,359,296 halves (4.72 MB)

    (void)hipMemsetAsync(counts, 0, 8 * sizeof(int), stream);
    setup_kernel<<<NNODES * 128 / 256, 256, 0, stream>>>(h, hT, counts, bucket);
    pack_msg_kernel<<<(NBOND * NLAY * 16 * 128 + 255) / 256, 256, 0, stream>>>(msgW, WpM);
    pack_gru_kernel<<<(2 * NTYPE * 2 * 16 * 384 + 255) / 256, 256, 0, stream>>>(Wih, Whh, WpG);

    for (int pass = 0; pass < 3; ++pass) {
        (void)hipMemsetAsync(m_non, 0, (size_t)NNODES * 128 * 4, stream);
        mlp_agg_mfma<<<dim3(NBOND, 128), 256, 0, stream>>>(hT, WpM, g, m_non, m_uni);
        gru_mfma<<<dim3(NNODES / 64, NTYPE), 256, 0, stream>>>(hT, m_non, m_uni, counts, bucket,
                                                               WpG, bih, bhh);
    }
}